// Round 4
// baseline (122.743 us; speedup 1.0000x reference)
//
#include <hip/hip_runtime.h>
#include <hip/hip_bf16.h>

// out[b,i,j,k] = sum_{p,q,r} x[b,p,q,r] W1[p,i] W2[q,j] W3[r,k]
// Stages contract r, then q, then p; each stage writes transposed so the next
// contracted axis is fast. R4 structure (vs R3):
//  - NO x staging in LDS: stage-A A-fragments load straight from global
//    (identical bf16 values; saves 64KB LDS round-trip + 2 barriers + VALU).
//  - Stage A -> stage B handoff is WAVE-LOCAL (wave w writes/reads yA rows
//    [64w,64w+64) only, p in {2w,2w+1}) -> no barrier needed, just in-wave
//    LDS ordering (compiler-tracked, same array).
//  - Only 2 block-wide barriers remain:
//      B_a: all fb reads done before yB writes clobber foreign rows (WAR)
//      B_b: yB complete before fc reads (RAW)
// LDS: one 64KB bf16 buffer, in-place, 8-granular XOR bank swizzle.
// MFMA 16x16x32 bf16 layouts as validated in R3 (absmax 0.036):
//   A/B lane l: k = 8*((l>>4)&3)+j ; C/D: col=l&15, row=4*((l>>4)&3)+reg.

typedef __attribute__((ext_vector_type(8))) short bf16x8;
typedef __attribute__((ext_vector_type(4))) float f32x4;

#define NROW 32768

__device__ __forceinline__ unsigned short f2b(float f) {
    union { float f; unsigned u; } v; v.f = f;
    unsigned r = v.u + 0x7fffu + ((v.u >> 16) & 1u);   // RNE bf16
    return (unsigned short)(r >> 16);
}

// swizzled element index: column XOR'd (8-granular) by row hash -> b128-safe
__device__ __forceinline__ int swz(int row, int col) {
    int s = ((row ^ (row >> 2) ^ (row >> 4)) & 3) << 3;
    return row * 32 + (col ^ s);
}

// weight fragment: lane (c,g) holds W[k=8g+j][n=16h+c], j=0..7 (k-consecutive)
__device__ __forceinline__ bf16x8 wfrag(const float* __restrict__ W, int h, int c, int g) {
    bf16x8 r;
#pragma unroll
    for (int j = 0; j < 8; ++j)
        r[j] = (short)f2b(W[(8 * g + j) * 32 + 16 * h + c]);
    return r;
}

// LDS fragment: row-major 32-col row, 8 contiguous cols at swizzled block
__device__ __forceinline__ bf16x8 ldsfrag(const unsigned short* buf, int row, int g) {
    int s = (row ^ (row >> 2) ^ (row >> 4)) & 3;
    union { uint4 u; bf16x8 b; } cv;
    cv.u = *(const uint4*)(buf + row * 32 + 8 * (g ^ s));
    return cv.b;
}

__global__ __launch_bounds__(1024, 8) void kron3_mfma(
    const float* __restrict__ x,  const float* __restrict__ W1,
    const float* __restrict__ W2, const float* __restrict__ W3,
    float* __restrict__ out)
{
    __shared__ unsigned short buf[NROW];            // 64 KiB bf16
    const int t = threadIdx.x;
    const int w = t >> 6, c = t & 15, g = (t >> 4) & 3;
    const float* __restrict__ xrow = x + (size_t)blockIdx.x * NROW;
    float* __restrict__ orow = out + (size_t)blockIdx.x * NROW;
    const f32x4 vzero = {0.f, 0.f, 0.f, 0.f};

    // ---- stage-A A-fragments straight from global (rows mA=(p,q), k=r) ----
    // lane (c,g): 8 consecutive fp32 at row 64w+16mt+c -> 2x float4, coalesced
    bf16x8 fa[4];
#pragma unroll
    for (int mt = 0; mt < 4; ++mt) {
        const float* src = xrow + (64 * w + 16 * mt + c) * 32 + 8 * g;
        float4 f0 = ((const float4*)src)[0];
        float4 f1 = ((const float4*)src)[1];
        bf16x8 r;
        r[0] = (short)f2b(f0.x); r[1] = (short)f2b(f0.y);
        r[2] = (short)f2b(f0.z); r[3] = (short)f2b(f0.w);
        r[4] = (short)f2b(f1.x); r[5] = (short)f2b(f1.y);
        r[6] = (short)f2b(f1.z); r[7] = (short)f2b(f1.w);
        fa[mt] = r;
    }
    bf16x8 wA[2];
    wA[0] = wfrag(W3, 0, c, g);
    wA[1] = wfrag(W3, 1, c, g);

    // ---- stage A: contract r.  yA[(p,k'),q] = sum_r x[(p,q),r] W3[r,k'] ----
    // writes land in wave-local rows [64w, 64w+64)  (p = 2w + (mt>>1))
#pragma unroll
    for (int nt = 0; nt < 2; ++nt) {
        const int kp = 16 * nt + c;
#pragma unroll
        for (int mt = 0; mt < 4; ++mt) {
            f32x4 a = __builtin_amdgcn_mfma_f32_16x16x32_bf16(fa[mt], wA[nt], vzero, 0, 0, 0);
            const int p  = 2 * w + (mt >> 1);
            const int q0 = 16 * (mt & 1) + 4 * g;
            unsigned lo = (unsigned)f2b(a[0]) | ((unsigned)f2b(a[1]) << 16);
            unsigned hi = (unsigned)f2b(a[2]) | ((unsigned)f2b(a[3]) << 16);
            *(uint2*)(buf + swz(p * 32 + kp, q0)) = make_uint2(lo, hi);
        }
    }

    // ---- stage B fragments: wave-local rows -> no block barrier needed ----
    bf16x8 fb[4];
#pragma unroll
    for (int mt = 0; mt < 4; ++mt)
        fb[mt] = ldsfrag(buf, 64 * w + 16 * mt + c, g);   // (p,k) rows, k=q
    bf16x8 wB[2];
    wB[0] = wfrag(W2, 0, c, g);
    wB[1] = wfrag(W2, 1, c, g);
    __syncthreads();                     // B_a: all yA reads done (WAR guard)

    // ---- stage B: contract q.  yB[(j,k),p] = sum_q yA[(p,k),q] W2[q,j] ----
    // swapped operands: D rows = j, cols = k (from fb's m-index)
#pragma unroll
    for (int jt = 0; jt < 2; ++jt) {
#pragma unroll
        for (int mt = 0; mt < 4; ++mt) {
            f32x4 a = __builtin_amdgcn_mfma_f32_16x16x32_bf16(wB[jt], fb[mt], vzero, 0, 0, 0);
            const int k = 16 * (mt & 1) + c;
            const int p = 2 * w + (mt >> 1);
#pragma unroll
            for (int rg = 0; rg < 4; ++rg) {
                const int j = 16 * jt + 4 * g + rg;
                buf[swz(j * 32 + k, p)] = f2b(a[rg]);   // scalar b16, swizzled
            }
        }
    }
    __syncthreads();                     // B_b: yB complete (RAW guard)

    // ---- stage C: contract p.  out[i,j,k] = sum_p yB[(j,k),p] W1[p,i] ----
    bf16x8 wC[2];
    wC[0] = wfrag(W1, 0, c, g);
    wC[1] = wfrag(W1, 1, c, g);
    bf16x8 fc[4];
#pragma unroll
    for (int mt = 0; mt < 4; ++mt)
        fc[mt] = ldsfrag(buf, 64 * w + 16 * mt + c, g);   // rows (j,k), k=p

#pragma unroll
    for (int nt = 0; nt < 2; ++nt) {
        const int i = 16 * nt + c;
#pragma unroll
        for (int mt = 0; mt < 4; ++mt) {
            f32x4 a = __builtin_amdgcn_mfma_f32_16x16x32_bf16(fc[mt], wC[nt], vzero, 0, 0, 0);
            const int j  = 2 * w + (mt >> 1);
            const int k0 = 16 * (mt & 1) + 4 * g;
            *(float4*)(orow + i * 1024 + j * 32 + k0) =
                make_float4(a[0], a[1], a[2], a[3]);      // 64B-coalesced
        }
    }
}

extern "C" void kernel_launch(void* const* d_in, const int* in_sizes, int n_in,
                              void* d_out, int out_size, void* d_ws, size_t ws_size,
                              hipStream_t stream) {
    const float* x  = (const float*)d_in[0];
    const float* W1 = (const float*)d_in[1];
    const float* W2 = (const float*)d_in[2];
    const float* W3 = (const float*)d_in[3];
    float* outp = (float*)d_out;

    const int batch = in_sizes[0] / NROW;             // 2048
    kron3_mfma<<<dim3(batch), dim3(1024), 0, stream>>>(x, W1, W2, W3, outp);
}